// Round 12
// baseline (562.659 us; speedup 1.0000x reference)
//
#include <hip/hip_runtime.h>
#include <hip/hip_cooperative_groups.h>

namespace cg = cooperative_groups;

#define NN 100000
#define NE 1600000
#define DD 128
#define CAP 56      // padded-CSR capacity; P(Poisson(16) >= 56) ~ 5e-15
#define NGROUP 256  // edge-slice groups for filtered scatter
#define NSTRIPE 32  // BN-stat stripes (blockIdx&31 -> 4 per XCD)

// ---------- bf16 helpers (manual, RNE) ----------
static __device__ __forceinline__ unsigned short f2b(float f) {
  unsigned int x = __float_as_uint(f);
  unsigned int r = x + 0x7fffu + ((x >> 16) & 1u);
  return (unsigned short)(r >> 16);
}
static __device__ __forceinline__ float b2f(unsigned short u) {
  return __uint_as_float(((unsigned int)u) << 16);
}

typedef __attribute__((ext_vector_type(8))) short short8;
typedef __attribute__((ext_vector_type(4))) float f32x4;

union V8 {
  uint4 u4;
  short8 s8;
  unsigned short us[8];
};

// ---------- front-end: bf16 cast + housekeeping + wprep fold ----------
// (edge pack dropped in R12: scatter reads ei directly -- it is not read-bound)
__global__ __launch_bounds__(256) void castpack_k(const float* __restrict__ x,
                                                  unsigned short* __restrict__ x16,
                                                  int* __restrict__ cnt,
                                                  float* __restrict__ stats,
                                                  const float* __restrict__ W1,
                                                  const float* __restrict__ W2,
                                                  const float* __restrict__ fW1,
                                                  const float* __restrict__ fW2,
                                                  unsigned short* __restrict__ wt) {
  const int tid = threadIdx.x;
  const int gid = blockIdx.x * 256 + tid;

  // ---- cast part: 8 fp32 -> 8 bf16 ----
  size_t i = (size_t)gid * 8;
  f32x4 a = *(const f32x4*)(x + i);
  f32x4 b = *(const f32x4*)(x + i + 4);
  V8 v;
#pragma unroll
  for (int j = 0; j < 4; ++j) {
    v.us[j] = f2b(a[j]);
    v.us[4 + j] = f2b(b[j]);
  }
  *(uint4*)(x16 + i) = v.u4;

  if (gid < NN) cnt[gid] = 0;
  if (gid < 4 * NSTRIPE * 256) stats[gid] = 0.f;

  // ---- wprep part (blocks 0..479): transpose+cast weights to bf16 wT[n][k] ----
  if (blockIdx.x < 480) {
    int bb = blockIdx.x;
    const float* src;
    int moff, N;
    if (bb < 192) {
      int m = bb >> 6;
      src = W1 + m * 16384;
      moff = m * 16384;
      N = 128;
      bb &= 63;
    } else if (bb < 384) {
      int m = (bb - 192) >> 6;
      src = W2 + m * 16384;
      moff = (3 + m) * 16384;
      N = 128;
      bb = (bb - 192) & 63;
    } else if (bb < 448) {
      src = fW1;
      moff = 6 * 16384;
      N = 128;
      bb -= 384;
    } else {
      src = fW2;
      moff = 7 * 16384;
      N = 64;
      bb -= 448;
    }
    int idx = bb * 256 + tid;  // n*128 + k
    int n = idx >> 7, k = idx & 127;
    if (n < N) wt[moff + idx] = f2b(src[(size_t)k * N + n]);
  }
}

// ---------- padded-CSR scatter from ei directly, XCD-range-filtered ----------
// Proven floor ~70 us (atomic+scattered-write machinery). Reads ei 8x instead
// of packed 8x -- scatter is NOT read-bound (R5/R6), so the extra bytes are
// free and the pack stage disappears. Per-block dtype ballot on wave 0.
__global__ __launch_bounds__(256) void scatter_k(const int* __restrict__ ei,
                                                 int* __restrict__ cnt,
                                                 int* __restrict__ csr) {
  __shared__ int modeS;
  if (threadIdx.x < 64) {
    int v = ei[2 * threadIdx.x + 1];
    unsigned long long b = __ballot(v != 0);
    if (threadIdx.x == 0) modeS = (b == 0ull) ? 1 : 0;
  }
  __syncthreads();
  const int mode = modeS;
  const int r = blockIdx.x & 7;
  const int g = blockIdx.x >> 3;
  const int lo = r * (NN / 8), hi = lo + (NN / 8);
  for (int e = g * 256 + threadIdx.x; e < NE; e += NGROUP * 256) {
    int s, d;
    if (mode) {  // int64 little-endian, values < 2^31: low word at even offset
      s = ((const int2*)ei)[e].x;
      d = ((const int2*)ei)[(size_t)NE + e].x;
    } else {
      s = ei[e];
      d = ei[NE + e];
    }
    if (d >= lo && d < hi) {
      int c = atomicAdd(&cnt[d], 1);
      if (c < CAP) csr[(size_t)d * CAP + c] = s;
    }
  }
}

// ---------- standalone gather (fallback path only) ----------
__global__ __launch_bounds__(256) void gather_k(const int* __restrict__ cnt,
                                                const int* __restrict__ csr,
                                                const unsigned short* __restrict__ x16,
                                                unsigned short* __restrict__ h16) {
  const int node = blockIdx.x * 16 + (threadIdx.x >> 4);
  const int l = threadIdx.x & 15;
  const int beg = node * CAP;
  const int end = beg + cnt[node];
  V8 v;
  v.u4 = *(const uint4*)(x16 + (size_t)node * DD + l * 8);
  float ac0[8], ac1[8];
#pragma unroll
  for (int j = 0; j < 8; ++j) {
    ac0[j] = b2f(v.us[j]);
    ac1[j] = 0.f;
  }
  int p = beg;
  for (; p + 2 <= end; p += 2) {
    const int s0 = csr[p], s1 = csr[p + 1];
    V8 w0, w1;
    w0.u4 = *(const uint4*)(x16 + (size_t)s0 * DD + l * 8);
    w1.u4 = *(const uint4*)(x16 + (size_t)s1 * DD + l * 8);
#pragma unroll
    for (int j = 0; j < 8; ++j) {
      ac0[j] += b2f(w0.us[j]);
      ac1[j] += b2f(w1.us[j]);
    }
  }
  if (p < end) {
    const int s0 = csr[p];
    V8 w0;
    w0.u4 = *(const uint4*)(x16 + (size_t)s0 * DD + l * 8);
#pragma unroll
    for (int j = 0; j < 8; ++j) ac0[j] += b2f(w0.us[j]);
  }
  V8 o;
#pragma unroll
  for (int j = 0; j < 8; ++j) o.us[j] = f2b(ac0[j] + ac1[j]);
  *(uint4*)(h16 + (size_t)node * DD + l * 8) = o.u4;
}

// ---------- cooperative fused layer: [gather+]gemm1+stats -> grid.sync -> BN+gemm2 ----------
// R12: GATHER=1 does the neighbor-sum IN-REGISTER inside phase 1 (R1's AMODE=3,
// retried in the persistent 24-wave regime). Each lane's fp32 accumulator IS
// its MFMA A-fragment -- no barrier between gather and MFMA, so waves skew:
// some gather (LLC-BW-bound) while others MFMA. h16 never materializes.
template <int SECONDCOLS, int SECEPI, int GATHER>
__global__ __launch_bounds__(512) void layer_k(const unsigned short* __restrict__ Aptr,
                                               const int* __restrict__ cnt,
                                               const int* __restrict__ csr,
                                               const unsigned short* __restrict__ wT1,
                                               const float* __restrict__ bias1,
                                               const unsigned short* __restrict__ wT2,
                                               const float* __restrict__ bias2,
                                               const float* __restrict__ gamma,
                                               const float* __restrict__ beta,
                                               unsigned short* __restrict__ t16,
                                               void* __restrict__ Cptr,
                                               float* __restrict__ stats,
                                               int ntiles) {
  __shared__ unsigned short bT[128][136];  // staged weights (W1 then W2)
  __shared__ float scS[128];
  __shared__ float shS[128];
  __shared__ float sS[128];
  __shared__ float s2S[128];
  const int tid = threadIdx.x;
  const int wv = tid >> 6;
  const int lane = tid & 63;
  const int l16 = lane & 15;
  const int quad = lane >> 4;

  // stage W1 (once per block) + zero block-stats
  for (int i = tid; i < 128 * 16; i += 512) {
    int n = i >> 4, k8 = (i & 15) << 3;
    *(uint4*)&bT[n][k8] = *(const uint4*)(wT1 + n * 128 + k8);
  }
  if (tid < 128) {
    sS[tid] = 0.f;
    s2S[tid] = 0.f;
  }
  __syncthreads();

  // ---- phase 1: t16 = (gathered A) @ W1^T + b1 (bf16), stats on rounded values ----
  for (int m = blockIdx.x; m < ntiles; m += gridDim.x) {
    const int arow = m * 128 + wv * 16 + l16;
    const bool rv = arow < NN;
    V8 afr[4];
    if (GATHER) {
      float ac[4][8];
#pragma unroll
      for (int kc = 0; kc < 4; ++kc)
#pragma unroll
        for (int j = 0; j < 8; ++j) ac[kc][j] = 0.f;
      if (rv) {
        const unsigned short* rowp = Aptr + (size_t)arow * DD + quad * 8;
#pragma unroll
        for (int kc = 0; kc < 4; ++kc) {
          V8 vv;
          vv.u4 = *(const uint4*)(rowp + kc * 32);
#pragma unroll
          for (int j = 0; j < 8; ++j) ac[kc][j] = b2f(vv.us[j]);
        }
        const int beg = arow * CAP;
        const int end = beg + cnt[arow];
        int p = beg;
        for (; p + 2 <= end; p += 2) {  // 8 x 16B loads in flight
          const int s0 = csr[p], s1 = csr[p + 1];
          const unsigned short* r0 = Aptr + (size_t)s0 * DD + quad * 8;
          const unsigned short* r1 = Aptr + (size_t)s1 * DD + quad * 8;
          V8 w0[4], w1[4];
#pragma unroll
          for (int kc = 0; kc < 4; ++kc) {
            w0[kc].u4 = *(const uint4*)(r0 + kc * 32);
            w1[kc].u4 = *(const uint4*)(r1 + kc * 32);
          }
#pragma unroll
          for (int kc = 0; kc < 4; ++kc)
#pragma unroll
            for (int j = 0; j < 8; ++j)
              ac[kc][j] += b2f(w0[kc].us[j]) + b2f(w1[kc].us[j]);
        }
        if (p < end) {
          const int s0 = csr[p];
          const unsigned short* r0 = Aptr + (size_t)s0 * DD + quad * 8;
#pragma unroll
          for (int kc = 0; kc < 4; ++kc) {
            V8 w0;
            w0.u4 = *(const uint4*)(r0 + kc * 32);
#pragma unroll
            for (int j = 0; j < 8; ++j) ac[kc][j] += b2f(w0.us[j]);
          }
        }
      }
#pragma unroll
      for (int kc = 0; kc < 4; ++kc)
#pragma unroll
        for (int j = 0; j < 8; ++j) afr[kc].us[j] = f2b(ac[kc][j]);
    } else {
#pragma unroll
      for (int kc = 0; kc < 4; ++kc) {
        if (rv) {
          afr[kc].u4 = *(const uint4*)(Aptr + (size_t)arow * DD + kc * 32 + quad * 8);
        } else {
          afr[kc].u4 = make_uint4(0u, 0u, 0u, 0u);
        }
      }
    }
    f32x4 acc[8];
#pragma unroll
    for (int nt = 0; nt < 8; ++nt) acc[nt] = (f32x4)(0.0f);
#pragma unroll
    for (int kc = 0; kc < 4; ++kc) {
      const int k0 = kc * 32 + quad * 8;
#pragma unroll
      for (int nt = 0; nt < 8; ++nt) {
        V8 bf;
        bf.u4 = *(const uint4*)&bT[nt * 16 + l16][k0];
        acc[nt] = __builtin_amdgcn_mfma_f32_16x16x32_bf16(afr[kc].s8, bf.s8, acc[nt], 0, 0, 0);
      }
    }
    const int r0 = m * 128 + wv * 16 + quad * 4;
#pragma unroll
    for (int nt = 0; nt < 8; ++nt) {
      const int col = nt * 16 + l16;
      const float bv = bias1[col];
      float s = 0.f, s2 = 0.f;
#pragma unroll
      for (int i = 0; i < 4; ++i) {
        const int r = r0 + i;
        if (r < NN) {
          unsigned short us = f2b(acc[nt][i] + bv);
          t16[(size_t)r * 128 + col] = us;
          float vr = b2f(us);
          s += vr;
          s2 += vr * vr;
        }
      }
      s += __shfl_xor(s, 16);
      s += __shfl_xor(s, 32);
      s2 += __shfl_xor(s2, 16);
      s2 += __shfl_xor(s2, 32);
      if (quad == 0) {
        atomicAdd(&sS[col], s);
        atomicAdd(&s2S[col], s2);
      }
    }
  }
  __syncthreads();
  if (tid < 128) {
    const int xs = (blockIdx.x & (NSTRIPE - 1)) * 256;  // striped flush
    atomicAdd(&stats[xs + tid], sS[tid]);
    atomicAdd(&stats[xs + 128 + tid], s2S[tid]);
  }

  cg::this_grid().sync();

  // ---- BN finalize + restage W2 into the same LDS buffer ----
  for (int i = tid; i < SECONDCOLS * 16; i += 512) {
    int n = i >> 4, k8 = (i & 15) << 3;
    *(uint4*)&bT[n][k8] = *(const uint4*)(wT2 + n * 128 + k8);
  }
  if (tid < 128) {
    float su = 0.f, sq = 0.f;
#pragma unroll
    for (int j = 0; j < NSTRIPE; ++j) {
      su += stats[j * 256 + tid];
      sq += stats[j * 256 + 128 + tid];
    }
    const float inv_n = 1.0f / (float)NN;
    float mu = su * inv_n;
    float var = sq * inv_n - mu * mu;
    float sc = gamma[tid] * rsqrtf(var + 1e-5f);
    scS[tid] = sc;
    shS[tid] = beta[tid] - mu * sc;
  }
  __syncthreads();

  // ---- phase 2: C = relu(BN(t)) @ W2^T + b2 ----
  for (int m = blockIdx.x; m < ntiles; m += gridDim.x) {
    const int arow = m * 128 + wv * 16 + l16;
    const bool rv = arow < NN;
    V8 afr[4];
#pragma unroll
    for (int kc = 0; kc < 4; ++kc) {
      if (rv) {
        afr[kc].u4 = *(const uint4*)(t16 + (size_t)arow * 128 + kc * 32 + quad * 8);
      } else {
        afr[kc].u4 = make_uint4(0u, 0u, 0u, 0u);
      }
    }
    f32x4 acc[SECONDCOLS / 16];
#pragma unroll
    for (int nt = 0; nt < SECONDCOLS / 16; ++nt) acc[nt] = (f32x4)(0.0f);
#pragma unroll
    for (int kc = 0; kc < 4; ++kc) {
      const int k0 = kc * 32 + quad * 8;
      V8 af = afr[kc];
#pragma unroll
      for (int j = 0; j < 8; ++j) {
        float f = fmaf(b2f(af.us[j]), scS[k0 + j], shS[k0 + j]);
        af.us[j] = f2b(fmaxf(f, 0.0f));
      }
#pragma unroll
      for (int nt = 0; nt < SECONDCOLS / 16; ++nt) {
        V8 bf;
        bf.u4 = *(const uint4*)&bT[nt * 16 + l16][k0];
        acc[nt] = __builtin_amdgcn_mfma_f32_16x16x32_bf16(af.s8, bf.s8, acc[nt], 0, 0, 0);
      }
    }
    const int r0 = m * 128 + wv * 16 + quad * 4;
#pragma unroll
    for (int nt = 0; nt < SECONDCOLS / 16; ++nt) {
      const int col = nt * 16 + l16;
      const float bv = bias2[col];
#pragma unroll
      for (int i = 0; i < 4; ++i) {
        const int r = r0 + i;
        if (r < NN) {
          float v = acc[nt][i] + bv;
          if (SECEPI == 1) {
            ((unsigned short*)Cptr)[(size_t)r * SECONDCOLS + col] = f2b(fmaxf(v, 0.0f));
          } else {
            ((float*)Cptr)[(size_t)r * SECONDCOLS + col] = v;
          }
        }
      }
    }
  }
}

// ---------- non-cooperative fallback GEMM (R7-exact, 32-stripe stats) ----------
template <int AMODE, int NCOLS, int EPI, int STATS>
__global__ __launch_bounds__(512) void gemm_k(const unsigned short* __restrict__ Aptr,
                                              const unsigned short* __restrict__ wT,
                                              const float* __restrict__ bias,
                                              const float* __restrict__ bn_stats,
                                              const float* __restrict__ gamma,
                                              const float* __restrict__ beta,
                                              void* __restrict__ Cptr,
                                              float* __restrict__ stats_out) {
  __shared__ unsigned short bT[NCOLS][136];
  __shared__ float biasS[NCOLS];
  __shared__ float scS[128];
  __shared__ float shS[128];
  __shared__ float sS[NCOLS];
  __shared__ float s2S[NCOLS];
  const int tid = threadIdx.x;
  const int wv = tid >> 6;
  const int lane = tid & 63;
  const int l16 = lane & 15;
  const int quad = lane >> 4;
  const int arow = blockIdx.x * 128 + wv * 16 + l16;
  const bool rv = arow < NN;

  V8 afr[4];
#pragma unroll
  for (int kc = 0; kc < 4; ++kc) {
    if (rv) {
      afr[kc].u4 = *(const uint4*)(Aptr + (size_t)arow * DD + kc * 32 + quad * 8);
    } else {
      afr[kc].u4 = make_uint4(0u, 0u, 0u, 0u);
    }
  }
  for (int i = tid; i < NCOLS * 16; i += 512) {
    int n = i >> 4, k8 = (i & 15) << 3;
    *(uint4*)&bT[n][k8] = *(const uint4*)(wT + n * 128 + k8);
  }
  if (tid < NCOLS) biasS[tid] = bias[tid];
  if (AMODE == 2 && tid < 128) {
    float su = 0.f, sq = 0.f;
#pragma unroll
    for (int j = 0; j < NSTRIPE; ++j) {
      su += bn_stats[j * 256 + tid];
      sq += bn_stats[j * 256 + 128 + tid];
    }
    const float inv_n = 1.0f / (float)NN;
    float mu = su * inv_n;
    float var = sq * inv_n - mu * mu;
    float sc = gamma[tid] * rsqrtf(var + 1e-5f);
    scS[tid] = sc;
    shS[tid] = beta[tid] - mu * sc;
  }
  if (STATS && tid < NCOLS) {
    sS[tid] = 0.f;
    s2S[tid] = 0.f;
  }
  __syncthreads();

  f32x4 acc[NCOLS / 16];
#pragma unroll
  for (int nt = 0; nt < NCOLS / 16; ++nt) acc[nt] = (f32x4)(0.0f);
#pragma unroll
  for (int kc = 0; kc < 4; ++kc) {
    const int k0 = kc * 32 + quad * 8;
    V8 af = afr[kc];
    if (AMODE == 2) {
#pragma unroll
      for (int j = 0; j < 8; ++j) {
        float f = fmaf(b2f(af.us[j]), scS[k0 + j], shS[k0 + j]);
        af.us[j] = f2b(fmaxf(f, 0.0f));
      }
    }
#pragma unroll
    for (int nt = 0; nt < NCOLS / 16; ++nt) {
      V8 bf;
      bf.u4 = *(const uint4*)&bT[nt * 16 + l16][k0];
      acc[nt] = __builtin_amdgcn_mfma_f32_16x16x32_bf16(af.s8, bf.s8, acc[nt], 0, 0, 0);
    }
  }
  const int r0 = blockIdx.x * 128 + wv * 16 + quad * 4;
#pragma unroll
  for (int nt = 0; nt < NCOLS / 16; ++nt) {
    const int col = nt * 16 + l16;
    const float bv = biasS[col];
    float s = 0.f, s2 = 0.f;
#pragma unroll
    for (int i = 0; i < 4; ++i) {
      const int r = r0 + i;
      if (r < NN) {
        float v = acc[nt][i] + bv;
        if (EPI == 1) v = fmaxf(v, 0.0f);
        if (EPI == 2) {
          ((float*)Cptr)[(size_t)r * NCOLS + col] = v;
        } else {
          unsigned short us = f2b(v);
          ((unsigned short*)Cptr)[(size_t)r * NCOLS + col] = us;
          if (STATS) {
            float vr = b2f(us);
            s += vr;
            s2 += vr * vr;
          }
        }
      }
    }
    if (STATS) {
      s += __shfl_xor(s, 16);
      s += __shfl_xor(s, 32);
      s2 += __shfl_xor(s2, 16);
      s2 += __shfl_xor(s2, 32);
      if (quad == 0) {
        atomicAdd(&sS[col], s);
        atomicAdd(&s2S[col], s2);
      }
    }
  }
  if (STATS) {
    __syncthreads();
    if (tid < NCOLS) {
      const int xs = (blockIdx.x & (NSTRIPE - 1)) * 256;
      atomicAdd(&stats_out[xs + tid], sS[tid]);
      atomicAdd(&stats_out[xs + 128 + tid], s2S[tid]);
    }
  }
}

// ---------- launch ----------
extern "C" void kernel_launch(void* const* d_in, const int* in_sizes, int n_in,
                              void* d_out, int out_size, void* d_ws, size_t ws_size,
                              hipStream_t stream) {
  const float* x = (const float*)d_in[0];
  const int* ei = (const int*)d_in[1];
  const float* W1 = (const float*)d_in[2];
  const float* b1 = (const float*)d_in[3];
  const float* g1 = (const float*)d_in[4];
  const float* be1 = (const float*)d_in[5];
  const float* W2 = (const float*)d_in[6];
  const float* b2 = (const float*)d_in[7];
  const float* fW1 = (const float*)d_in[8];
  const float* fb1 = (const float*)d_in[9];
  const float* fg1 = (const float*)d_in[10];
  const float* fbe1 = (const float*)d_in[11];
  const float* fW2 = (const float*)d_in[12];
  const float* fb2 = (const float*)d_in[13];

  char* ws = (char*)d_ws;
  unsigned short* x16 = (unsigned short*)ws;                       // 25.6 MB
  unsigned short* h16 = (unsigned short*)(ws + (size_t)25600000);  // 25.6 MB (fallback only)
  unsigned short* t16 = (unsigned short*)(ws + (size_t)51200000);  // 25.6 MB
  int* csr = (int*)(ws + (size_t)76800000);       // NN*CAP*4 = 22.4 MB
  int* cnt = (int*)(ws + (size_t)99200000);       // 400 KB
  float* stats = (float*)(ws + (size_t)99600000); // 128 KB: 4 slots x 32 stripes x 256
  unsigned short* wt = (unsigned short*)(ws + (size_t)99731072);   // 262 KB

  const int vecBlocks = (NN * DD) / (256 * 8);  // 6250
  const int gemmBlocks = (NN + 127) / 128;      // 782
  const int filtBlocks = NGROUP * 8;            // 2048
  const int nodeBlocks = NN / 16;               // 6250

  // cooperative-launch feasibility (host-side pure queries; graph-safe)
  int dev = 0, coop = 0;
  hipGetDevice(&dev);
  hipDeviceGetAttribute(&coop, hipDeviceAttributeCooperativeLaunch, dev);
  int occA = 0, occB = 0;
  hipOccupancyMaxActiveBlocksPerMultiprocessor(&occA, layer_k<128, 1, 1>, 512, 0);
  hipOccupancyMaxActiveBlocksPerMultiprocessor(&occB, layer_k<64, 2, 0>, 512, 0);
  int gridA = occA > 0 ? occA * 256 : 0;
  int gridB = occB > 0 ? occB * 256 : 0;
  if (gridA > gemmBlocks) gridA = gemmBlocks;
  if (gridB > gemmBlocks) gridB = gemmBlocks;
  const bool useCoop = (coop != 0) && (gridA > 0) && (gridB > 0);

  castpack_k<<<vecBlocks, 256, 0, stream>>>(x, x16, cnt, stats, W1, W2, fW1,
                                            fW2, wt);
  scatter_k<<<filtBlocks, 256, 0, stream>>>(ei, cnt, csr);

  int ntiles = gemmBlocks;
  for (int l = 0; l < 3; ++l) {
    if (useCoop) {
      const unsigned short* Ap = x16;
      const int* cp_ = cnt;
      const int* cs_ = csr;
      const unsigned short* w1p = wt + (size_t)l * 16384;
      const float* b1p = b1 + l * 128;
      const unsigned short* w2p = wt + (size_t)(3 + l) * 16384;
      const float* b2p = b2 + l * 128;
      const float* gp = g1 + l * 128;
      const float* bep = be1 + l * 128;
      unsigned short* tp = t16;
      void* cp = (void*)x16;
      float* sp = stats + 256 * NSTRIPE * l;
      void* args[] = {&Ap, &cp_, &cs_, &w1p, &b1p, &w2p, &b2p, &gp, &bep,
                      &tp, &cp, &sp, &ntiles};
      hipLaunchCooperativeKernel((void*)layer_k<128, 1, 1>, dim3(gridA),
                                 dim3(512), args, 0, stream);
    } else {
      gather_k<<<nodeBlocks, 256, 0, stream>>>(cnt, csr, x16, h16);
      gemm_k<1, 128, 0, 1><<<gemmBlocks, 512, 0, stream>>>(
          h16, wt + (size_t)l * 16384, b1 + l * 128, nullptr, nullptr, nullptr,
          t16, stats + 256 * NSTRIPE * l);
      gemm_k<2, 128, 1, 0><<<gemmBlocks, 512, 0, stream>>>(
          t16, wt + (size_t)(3 + l) * 16384, b2 + l * 128, stats + 256 * NSTRIPE * l,
          g1 + l * 128, be1 + l * 128, x16, nullptr);
    }
  }

  // final MLP: Linear -> BN -> ReLU -> Linear, out fp32 [NN x 64]
  if (useCoop) {
    const unsigned short* Ap = x16;
    const int* cp_ = nullptr;
    const int* cs_ = nullptr;
    const unsigned short* w1p = wt + (size_t)6 * 16384;
    const float* b1p = fb1;
    const unsigned short* w2p = wt + (size_t)7 * 16384;
    const float* b2p = fb2;
    const float* gp = fg1;
    const float* bep = fbe1;
    unsigned short* tp = t16;
    void* cp = d_out;
    float* sp = stats + 256 * NSTRIPE * 3;
    void* args[] = {&Ap, &cp_, &cs_, &w1p, &b1p, &w2p, &b2p, &gp, &bep,
                    &tp, &cp, &sp, &ntiles};
    hipLaunchCooperativeKernel((void*)layer_k<64, 2, 0>, dim3(gridB), dim3(512),
                               args, 0, stream);
  } else {
    gemm_k<1, 128, 0, 1><<<gemmBlocks, 512, 0, stream>>>(
        x16, wt + (size_t)6 * 16384, fb1, nullptr, nullptr, nullptr, t16,
        stats + 256 * NSTRIPE * 3);
    gemm_k<2, 64, 2, 0><<<gemmBlocks, 512, 0, stream>>>(
        t16, wt + (size_t)7 * 16384, fb2, stats + 256 * NSTRIPE * 3, fg1, fbe1,
        (float*)d_out, nullptr);
  }
}

// Round 13
// 549.501 us; speedup vs baseline: 1.0239x; 1.0239x over previous
//
#include <hip/hip_runtime.h>
#include <hip/hip_cooperative_groups.h>

namespace cg = cooperative_groups;

#define NN 100000
#define NE 1600000
#define DD 128
#define CAP 56      // padded-CSR capacity; P(Poisson(16) >= 56) ~ 5e-15
#define NGROUP 256  // edge-slice groups for filtered scatter
#define NSTRIPE 32  // BN-stat stripes (blockIdx&31 -> 4 per XCD)
#define SCATB 2048  // scatter blocks inside front_k (NGROUP*8)

// ---------- bf16 helpers (manual, RNE) ----------
static __device__ __forceinline__ unsigned short f2b(float f) {
  unsigned int x = __float_as_uint(f);
  unsigned int r = x + 0x7fffu + ((x >> 16) & 1u);
  return (unsigned short)(r >> 16);
}
static __device__ __forceinline__ float b2f(unsigned short u) {
  return __uint_as_float(((unsigned int)u) << 16);
}

typedef __attribute__((ext_vector_type(8))) short short8;
typedef __attribute__((ext_vector_type(4))) float f32x4;

union V8 {
  uint4 u4;
  short8 s8;
  unsigned short us[8];
};

// ---------- merged front-end: scatter (blocks 0..2047) || castpack (rest) ----------
// Scatter is atomic-latency-bound (23% HBM, VALU 5%); castpack is BW-bound.
// No data dependency between them (scatter reads ei directly -- R12-proven;
// cnt is zeroed by hipMemsetAsync before launch), so co-scheduling overlaps
// ~26 us of castpack under scatter's 70 us instead of serializing.
// Scatter keeps blockIdx 0..2047 -> the blockIdx&7 XCD round-robin mapping
// is identical to the standalone kernel's.
__global__ __launch_bounds__(256) void front_k(const int* __restrict__ ei,
                                               int* __restrict__ cnt,
                                               int* __restrict__ csr,
                                               const float* __restrict__ x,
                                               unsigned short* __restrict__ x16,
                                               float* __restrict__ stats,
                                               const float* __restrict__ W1,
                                               const float* __restrict__ W2,
                                               const float* __restrict__ fW1,
                                               const float* __restrict__ fW2,
                                               unsigned short* __restrict__ wt) {
  const int tid = threadIdx.x;
  if (blockIdx.x < SCATB) {
    // ---- scatter part: padded-CSR scatter from ei, XCD-range-filtered ----
    __shared__ int modeS;
    if (tid < 64) {
      int v = ei[2 * tid + 1];
      unsigned long long b = __ballot(v != 0);
      if (tid == 0) modeS = (b == 0ull) ? 1 : 0;
    }
    __syncthreads();
    const int mode = modeS;
    const int r = blockIdx.x & 7;
    const int g = blockIdx.x >> 3;
    const int lo = r * (NN / 8), hi = lo + (NN / 8);
    for (int e = g * 256 + tid; e < NE; e += NGROUP * 256) {
      int s, d;
      if (mode) {  // int64 little-endian, values < 2^31: low word at even offset
        s = ((const int2*)ei)[e].x;
        d = ((const int2*)ei)[(size_t)NE + e].x;
      } else {
        s = ei[e];
        d = ei[NE + e];
      }
      if (d >= lo && d < hi) {
        int c = atomicAdd(&cnt[d], 1);
        if (c < CAP) csr[(size_t)d * CAP + c] = s;
      }
    }
    return;
  }

  // ---- castpack part: bf16 cast + stats-zero + wprep fold ----
  const int cb = blockIdx.x - SCATB;
  const int gid = cb * 256 + tid;
  size_t i = (size_t)gid * 8;
  f32x4 a = *(const f32x4*)(x + i);
  f32x4 b = *(const f32x4*)(x + i + 4);
  V8 v;
#pragma unroll
  for (int j = 0; j < 4; ++j) {
    v.us[j] = f2b(a[j]);
    v.us[4 + j] = f2b(b[j]);
  }
  *(uint4*)(x16 + i) = v.u4;

  if (gid < 4 * NSTRIPE * 256) stats[gid] = 0.f;

  if (cb < 480) {
    int bb = cb;
    const float* src;
    int moff, N;
    if (bb < 192) {
      int m = bb >> 6;
      src = W1 + m * 16384;
      moff = m * 16384;
      N = 128;
      bb &= 63;
    } else if (bb < 384) {
      int m = (bb - 192) >> 6;
      src = W2 + m * 16384;
      moff = (3 + m) * 16384;
      N = 128;
      bb = (bb - 192) & 63;
    } else if (bb < 448) {
      src = fW1;
      moff = 6 * 16384;
      N = 128;
      bb -= 384;
    } else {
      src = fW2;
      moff = 7 * 16384;
      N = 64;
      bb -= 448;
    }
    int idx = bb * 256 + tid;  // n*128 + k
    int n = idx >> 7, k = idx & 127;
    if (n < N) wt[moff + idx] = f2b(src[(size_t)k * N + n]);
  }
}

// ---------- gather-reduce (R11-exact, 8-in-flight / 2-accumulator) ----------
__global__ __launch_bounds__(256) void gather_k(const int* __restrict__ cnt,
                                                const int* __restrict__ csr,
                                                const unsigned short* __restrict__ x16,
                                                unsigned short* __restrict__ h16) {
  const int node = blockIdx.x * 16 + (threadIdx.x >> 4);
  const int l = threadIdx.x & 15;
  const int beg = node * CAP;
  const int end = beg + cnt[node];
  V8 v;
  v.u4 = *(const uint4*)(x16 + (size_t)node * DD + l * 8);
  float ac0[8], ac1[8];
#pragma unroll
  for (int j = 0; j < 8; ++j) {
    ac0[j] = b2f(v.us[j]);
    ac1[j] = 0.f;
  }
  int p = beg;
  for (; p + 8 <= end; p += 8) {
    const int s0 = csr[p], s1 = csr[p + 1], s2 = csr[p + 2], s3 = csr[p + 3];
    const int s4 = csr[p + 4], s5 = csr[p + 5], s6 = csr[p + 6], s7 = csr[p + 7];
    V8 w0, w1, w2, w3, w4, w5, w6, w7;
    w0.u4 = *(const uint4*)(x16 + (size_t)s0 * DD + l * 8);
    w1.u4 = *(const uint4*)(x16 + (size_t)s1 * DD + l * 8);
    w2.u4 = *(const uint4*)(x16 + (size_t)s2 * DD + l * 8);
    w3.u4 = *(const uint4*)(x16 + (size_t)s3 * DD + l * 8);
    w4.u4 = *(const uint4*)(x16 + (size_t)s4 * DD + l * 8);
    w5.u4 = *(const uint4*)(x16 + (size_t)s5 * DD + l * 8);
    w6.u4 = *(const uint4*)(x16 + (size_t)s6 * DD + l * 8);
    w7.u4 = *(const uint4*)(x16 + (size_t)s7 * DD + l * 8);
#pragma unroll
    for (int j = 0; j < 8; ++j) {
      ac0[j] += (b2f(w0.us[j]) + b2f(w2.us[j])) + (b2f(w4.us[j]) + b2f(w6.us[j]));
      ac1[j] += (b2f(w1.us[j]) + b2f(w3.us[j])) + (b2f(w5.us[j]) + b2f(w7.us[j]));
    }
  }
  for (; p + 2 <= end; p += 2) {
    const int s0 = csr[p], s1 = csr[p + 1];
    V8 w0, w1;
    w0.u4 = *(const uint4*)(x16 + (size_t)s0 * DD + l * 8);
    w1.u4 = *(const uint4*)(x16 + (size_t)s1 * DD + l * 8);
#pragma unroll
    for (int j = 0; j < 8; ++j) {
      ac0[j] += b2f(w0.us[j]);
      ac1[j] += b2f(w1.us[j]);
    }
  }
  if (p < end) {
    const int s0 = csr[p];
    V8 w0;
    w0.u4 = *(const uint4*)(x16 + (size_t)s0 * DD + l * 8);
#pragma unroll
    for (int j = 0; j < 8; ++j) ac0[j] += b2f(w0.us[j]);
  }
  V8 o;
#pragma unroll
  for (int j = 0; j < 8; ++j) o.us[j] = f2b(ac0[j] + ac1[j]);
  *(uint4*)(h16 + (size_t)node * DD + l * 8) = o.u4;
}

// ---------- cooperative fused layer (R11-exact, 32-stripe stats) ----------
template <int SECONDCOLS, int SECEPI>
__global__ __launch_bounds__(512) void layer_k(const unsigned short* __restrict__ Aptr,
                                               const unsigned short* __restrict__ wT1,
                                               const float* __restrict__ bias1,
                                               const unsigned short* __restrict__ wT2,
                                               const float* __restrict__ bias2,
                                               const float* __restrict__ gamma,
                                               const float* __restrict__ beta,
                                               unsigned short* __restrict__ t16,
                                               void* __restrict__ Cptr,
                                               float* __restrict__ stats,
                                               int ntiles) {
  __shared__ unsigned short bT[128][136];  // staged weights (W1 then W2)
  __shared__ float scS[128];
  __shared__ float shS[128];
  __shared__ float sS[128];
  __shared__ float s2S[128];
  const int tid = threadIdx.x;
  const int wv = tid >> 6;
  const int lane = tid & 63;
  const int l16 = lane & 15;
  const int quad = lane >> 4;

  // stage W1 (once per block) + zero block-stats
  for (int i = tid; i < 128 * 16; i += 512) {
    int n = i >> 4, k8 = (i & 15) << 3;
    *(uint4*)&bT[n][k8] = *(const uint4*)(wT1 + n * 128 + k8);
  }
  if (tid < 128) {
    sS[tid] = 0.f;
    s2S[tid] = 0.f;
  }
  __syncthreads();

  // ---- phase 1: t16 = A @ W1^T + b1 (bf16), stats on rounded values ----
  for (int m = blockIdx.x; m < ntiles; m += gridDim.x) {
    const int arow = m * 128 + wv * 16 + l16;
    const bool rv = arow < NN;
    V8 afr[4];
#pragma unroll
    for (int kc = 0; kc < 4; ++kc) {
      if (rv) {
        afr[kc].u4 = *(const uint4*)(Aptr + (size_t)arow * DD + kc * 32 + quad * 8);
      } else {
        afr[kc].u4 = make_uint4(0u, 0u, 0u, 0u);
      }
    }
    f32x4 acc[8];
#pragma unroll
    for (int nt = 0; nt < 8; ++nt) acc[nt] = (f32x4)(0.0f);
#pragma unroll
    for (int kc = 0; kc < 4; ++kc) {
      const int k0 = kc * 32 + quad * 8;
#pragma unroll
      for (int nt = 0; nt < 8; ++nt) {
        V8 bf;
        bf.u4 = *(const uint4*)&bT[nt * 16 + l16][k0];
        acc[nt] = __builtin_amdgcn_mfma_f32_16x16x32_bf16(afr[kc].s8, bf.s8, acc[nt], 0, 0, 0);
      }
    }
    const int r0 = m * 128 + wv * 16 + quad * 4;
#pragma unroll
    for (int nt = 0; nt < 8; ++nt) {
      const int col = nt * 16 + l16;
      const float bv = bias1[col];
      float s = 0.f, s2 = 0.f;
#pragma unroll
      for (int i = 0; i < 4; ++i) {
        const int r = r0 + i;
        if (r < NN) {
          unsigned short us = f2b(acc[nt][i] + bv);
          t16[(size_t)r * 128 + col] = us;
          float vr = b2f(us);
          s += vr;
          s2 += vr * vr;
        }
      }
      s += __shfl_xor(s, 16);
      s += __shfl_xor(s, 32);
      s2 += __shfl_xor(s2, 16);
      s2 += __shfl_xor(s2, 32);
      if (quad == 0) {
        atomicAdd(&sS[col], s);
        atomicAdd(&s2S[col], s2);
      }
    }
  }
  __syncthreads();
  if (tid < 128) {
    const int xs = (blockIdx.x & (NSTRIPE - 1)) * 256;  // striped flush
    atomicAdd(&stats[xs + tid], sS[tid]);
    atomicAdd(&stats[xs + 128 + tid], s2S[tid]);
  }

  cg::this_grid().sync();

  // ---- BN finalize + restage W2 into the same LDS buffer ----
  for (int i = tid; i < SECONDCOLS * 16; i += 512) {
    int n = i >> 4, k8 = (i & 15) << 3;
    *(uint4*)&bT[n][k8] = *(const uint4*)(wT2 + n * 128 + k8);
  }
  if (tid < 128) {
    float su = 0.f, sq = 0.f;
#pragma unroll
    for (int j = 0; j < NSTRIPE; ++j) {
      su += stats[j * 256 + tid];
      sq += stats[j * 256 + 128 + tid];
    }
    const float inv_n = 1.0f / (float)NN;
    float mu = su * inv_n;
    float var = sq * inv_n - mu * mu;
    float sc = gamma[tid] * rsqrtf(var + 1e-5f);
    scS[tid] = sc;
    shS[tid] = beta[tid] - mu * sc;
  }
  __syncthreads();

  // ---- phase 2: C = relu(BN(t)) @ W2^T + b2 ----
  for (int m = blockIdx.x; m < ntiles; m += gridDim.x) {
    const int arow = m * 128 + wv * 16 + l16;
    const bool rv = arow < NN;
    V8 afr[4];
#pragma unroll
    for (int kc = 0; kc < 4; ++kc) {
      if (rv) {
        afr[kc].u4 = *(const uint4*)(t16 + (size_t)arow * 128 + kc * 32 + quad * 8);
      } else {
        afr[kc].u4 = make_uint4(0u, 0u, 0u, 0u);
      }
    }
    f32x4 acc[SECONDCOLS / 16];
#pragma unroll
    for (int nt = 0; nt < SECONDCOLS / 16; ++nt) acc[nt] = (f32x4)(0.0f);
#pragma unroll
    for (int kc = 0; kc < 4; ++kc) {
      const int k0 = kc * 32 + quad * 8;
      V8 af = afr[kc];
#pragma unroll
      for (int j = 0; j < 8; ++j) {
        float f = fmaf(b2f(af.us[j]), scS[k0 + j], shS[k0 + j]);
        af.us[j] = f2b(fmaxf(f, 0.0f));
      }
#pragma unroll
      for (int nt = 0; nt < SECONDCOLS / 16; ++nt) {
        V8 bf;
        bf.u4 = *(const uint4*)&bT[nt * 16 + l16][k0];
        acc[nt] = __builtin_amdgcn_mfma_f32_16x16x32_bf16(af.s8, bf.s8, acc[nt], 0, 0, 0);
      }
    }
    const int r0 = m * 128 + wv * 16 + quad * 4;
#pragma unroll
    for (int nt = 0; nt < SECONDCOLS / 16; ++nt) {
      const int col = nt * 16 + l16;
      const float bv = bias2[col];
#pragma unroll
      for (int i = 0; i < 4; ++i) {
        const int r = r0 + i;
        if (r < NN) {
          float v = acc[nt][i] + bv;
          if (SECEPI == 1) {
            ((unsigned short*)Cptr)[(size_t)r * SECONDCOLS + col] = f2b(fmaxf(v, 0.0f));
          } else {
            ((float*)Cptr)[(size_t)r * SECONDCOLS + col] = v;
          }
        }
      }
    }
  }
}

// ---------- non-cooperative fallback GEMM (R7-exact, 32-stripe stats) ----------
template <int AMODE, int NCOLS, int EPI, int STATS>
__global__ __launch_bounds__(512) void gemm_k(const unsigned short* __restrict__ Aptr,
                                              const unsigned short* __restrict__ wT,
                                              const float* __restrict__ bias,
                                              const float* __restrict__ bn_stats,
                                              const float* __restrict__ gamma,
                                              const float* __restrict__ beta,
                                              void* __restrict__ Cptr,
                                              float* __restrict__ stats_out) {
  __shared__ unsigned short bT[NCOLS][136];
  __shared__ float biasS[NCOLS];
  __shared__ float scS[128];
  __shared__ float shS[128];
  __shared__ float sS[NCOLS];
  __shared__ float s2S[NCOLS];
  const int tid = threadIdx.x;
  const int wv = tid >> 6;
  const int lane = tid & 63;
  const int l16 = lane & 15;
  const int quad = lane >> 4;
  const int arow = blockIdx.x * 128 + wv * 16 + l16;
  const bool rv = arow < NN;

  V8 afr[4];
#pragma unroll
  for (int kc = 0; kc < 4; ++kc) {
    if (rv) {
      afr[kc].u4 = *(const uint4*)(Aptr + (size_t)arow * DD + kc * 32 + quad * 8);
    } else {
      afr[kc].u4 = make_uint4(0u, 0u, 0u, 0u);
    }
  }
  for (int i = tid; i < NCOLS * 16; i += 512) {
    int n = i >> 4, k8 = (i & 15) << 3;
    *(uint4*)&bT[n][k8] = *(const uint4*)(wT + n * 128 + k8);
  }
  if (tid < NCOLS) biasS[tid] = bias[tid];
  if (AMODE == 2 && tid < 128) {
    float su = 0.f, sq = 0.f;
#pragma unroll
    for (int j = 0; j < NSTRIPE; ++j) {
      su += bn_stats[j * 256 + tid];
      sq += bn_stats[j * 256 + 128 + tid];
    }
    const float inv_n = 1.0f / (float)NN;
    float mu = su * inv_n;
    float var = sq * inv_n - mu * mu;
    float sc = gamma[tid] * rsqrtf(var + 1e-5f);
    scS[tid] = sc;
    shS[tid] = beta[tid] - mu * sc;
  }
  if (STATS && tid < NCOLS) {
    sS[tid] = 0.f;
    s2S[tid] = 0.f;
  }
  __syncthreads();

  f32x4 acc[NCOLS / 16];
#pragma unroll
  for (int nt = 0; nt < NCOLS / 16; ++nt) acc[nt] = (f32x4)(0.0f);
#pragma unroll
  for (int kc = 0; kc < 4; ++kc) {
    const int k0 = kc * 32 + quad * 8;
    V8 af = afr[kc];
    if (AMODE == 2) {
#pragma unroll
      for (int j = 0; j < 8; ++j) {
        float f = fmaf(b2f(af.us[j]), scS[k0 + j], shS[k0 + j]);
        af.us[j] = f2b(fmaxf(f, 0.0f));
      }
    }
#pragma unroll
    for (int nt = 0; nt < NCOLS / 16; ++nt) {
      V8 bf;
      bf.u4 = *(const uint4*)&bT[nt * 16 + l16][k0];
      acc[nt] = __builtin_amdgcn_mfma_f32_16x16x32_bf16(af.s8, bf.s8, acc[nt], 0, 0, 0);
    }
  }
  const int r0 = blockIdx.x * 128 + wv * 16 + quad * 4;
#pragma unroll
  for (int nt = 0; nt < NCOLS / 16; ++nt) {
    const int col = nt * 16 + l16;
    const float bv = biasS[col];
    float s = 0.f, s2 = 0.f;
#pragma unroll
    for (int i = 0; i < 4; ++i) {
      const int r = r0 + i;
      if (r < NN) {
        float v = acc[nt][i] + bv;
        if (EPI == 1) v = fmaxf(v, 0.0f);
        if (EPI == 2) {
          ((float*)Cptr)[(size_t)r * NCOLS + col] = v;
        } else {
          unsigned short us = f2b(v);
          ((unsigned short*)Cptr)[(size_t)r * NCOLS + col] = us;
          if (STATS) {
            float vr = b2f(us);
            s += vr;
            s2 += vr * vr;
          }
        }
      }
    }
    if (STATS) {
      s += __shfl_xor(s, 16);
      s += __shfl_xor(s, 32);
      s2 += __shfl_xor(s2, 16);
      s2 += __shfl_xor(s2, 32);
      if (quad == 0) {
        atomicAdd(&sS[col], s);
        atomicAdd(&s2S[col], s2);
      }
    }
  }
  if (STATS) {
    __syncthreads();
    if (tid < NCOLS) {
      const int xs = (blockIdx.x & (NSTRIPE - 1)) * 256;
      atomicAdd(&stats_out[xs + tid], sS[tid]);
      atomicAdd(&stats_out[xs + 128 + tid], s2S[tid]);
    }
  }
}

// ---------- launch ----------
extern "C" void kernel_launch(void* const* d_in, const int* in_sizes, int n_in,
                              void* d_out, int out_size, void* d_ws, size_t ws_size,
                              hipStream_t stream) {
  const float* x = (const float*)d_in[0];
  const int* ei = (const int*)d_in[1];
  const float* W1 = (const float*)d_in[2];
  const float* b1 = (const float*)d_in[3];
  const float* g1 = (const float*)d_in[4];
  const float* be1 = (const float*)d_in[5];
  const float* W2 = (const float*)d_in[6];
  const float* b2 = (const float*)d_in[7];
  const float* fW1 = (const float*)d_in[8];
  const float* fb1 = (const float*)d_in[9];
  const float* fg1 = (const float*)d_in[10];
  const float* fbe1 = (const float*)d_in[11];
  const float* fW2 = (const float*)d_in[12];
  const float* fb2 = (const float*)d_in[13];

  char* ws = (char*)d_ws;
  unsigned short* x16 = (unsigned short*)ws;                       // 25.6 MB
  unsigned short* h16 = (unsigned short*)(ws + (size_t)25600000);  // 25.6 MB
  unsigned short* t16 = (unsigned short*)(ws + (size_t)51200000);  // 25.6 MB
  int* csr = (int*)(ws + (size_t)76800000);       // NN*CAP*4 = 22.4 MB
  int* cnt = (int*)(ws + (size_t)99200000);       // 400 KB
  float* stats = (float*)(ws + (size_t)99600000); // 128 KB: 4 slots x 32 stripes x 256
  unsigned short* wt = (unsigned short*)(ws + (size_t)99731072);   // 262 KB

  const int vecBlocks = (NN * DD) / (256 * 8);  // 6250
  const int gemmBlocks = (NN + 127) / 128;      // 782
  const int nodeBlocks = NN / 16;               // 6250

  // cooperative-launch feasibility (host-side pure queries; graph-safe)
  int dev = 0, coop = 0;
  hipGetDevice(&dev);
  hipDeviceGetAttribute(&coop, hipDeviceAttributeCooperativeLaunch, dev);
  int occA = 0, occB = 0;
  hipOccupancyMaxActiveBlocksPerMultiprocessor(&occA, layer_k<128, 1>, 512, 0);
  hipOccupancyMaxActiveBlocksPerMultiprocessor(&occB, layer_k<64, 2>, 512, 0);
  int gridA = occA > 0 ? occA * 256 : 0;
  int gridB = occB > 0 ? occB * 256 : 0;
  if (gridA > gemmBlocks) gridA = gemmBlocks;
  if (gridB > gemmBlocks) gridB = gemmBlocks;
  const bool useCoop = (coop != 0) && (gridA > 0) && (gridB > 0);

  hipMemsetAsync(cnt, 0, NN * sizeof(int), stream);
  front_k<<<SCATB + vecBlocks, 256, 0, stream>>>(ei, cnt, csr, x, x16, stats,
                                                 W1, W2, fW1, fW2, wt);

  int ntiles = gemmBlocks;
  for (int l = 0; l < 3; ++l) {
    gather_k<<<nodeBlocks, 256, 0, stream>>>(cnt, csr, x16, h16);
    if (useCoop) {
      const unsigned short* Ap = h16;
      const unsigned short* w1p = wt + (size_t)l * 16384;
      const float* b1p = b1 + l * 128;
      const unsigned short* w2p = wt + (size_t)(3 + l) * 16384;
      const float* b2p = b2 + l * 128;
      const float* gp = g1 + l * 128;
      const float* bep = be1 + l * 128;
      unsigned short* tp = t16;
      void* cp = (void*)x16;
      float* sp = stats + 256 * NSTRIPE * l;
      void* args[] = {&Ap, &w1p, &b1p, &w2p, &b2p, &gp, &bep, &tp, &cp, &sp, &ntiles};
      hipLaunchCooperativeKernel((void*)layer_k<128, 1>, dim3(gridA), dim3(512),
                                 args, 0, stream);
    } else {
      gemm_k<1, 128, 0, 1><<<gemmBlocks, 512, 0, stream>>>(
          h16, wt + (size_t)l * 16384, b1 + l * 128, nullptr, nullptr, nullptr,
          t16, stats + 256 * NSTRIPE * l);
      gemm_k<2, 128, 1, 0><<<gemmBlocks, 512, 0, stream>>>(
          t16, wt + (size_t)(3 + l) * 16384, b2 + l * 128, stats + 256 * NSTRIPE * l,
          g1 + l * 128, be1 + l * 128, x16, nullptr);
    }
  }

  // final MLP: Linear -> BN -> ReLU -> Linear, out fp32 [NN x 64]
  if (useCoop) {
    const unsigned short* Ap = x16;
    const unsigned short* w1p = wt + (size_t)6 * 16384;
    const float* b1p = fb1;
    const unsigned short* w2p = wt + (size_t)7 * 16384;
    const float* b2p = fb2;
    const float* gp = fg1;
    const float* bep = fbe1;
    unsigned short* tp = t16;
    void* cp = d_out;
    float* sp = stats + 256 * NSTRIPE * 3;
    void* args[] = {&Ap, &w1p, &b1p, &w2p, &b2p, &gp, &bep, &tp, &cp, &sp, &ntiles};
    hipLaunchCooperativeKernel((void*)layer_k<64, 2>, dim3(gridB), dim3(512),
                               args, 0, stream);
  } else {
    gemm_k<1, 128, 0, 1><<<gemmBlocks, 512, 0, stream>>>(
        x16, wt + (size_t)6 * 16384, fb1, nullptr, nullptr, nullptr, t16,
        stats + 256 * NSTRIPE * 3);
    gemm_k<2, 64, 2, 0><<<gemmBlocks, 512, 0, stream>>>(
        t16, wt + (size_t)7 * 16384, fb2, stats + 256 * NSTRIPE * 3, fg1, fbe1,
        (float*)d_out, nullptr);
  }
}